// Round 3
// baseline (5348.215 us; speedup 1.0000x reference)
//
#include <hip/hip_runtime.h>
#include <hip/hip_bf16.h>

// Problem constants
#define BATCH   64
#define SEQ     512
#define DMODEL  256
#define HIDDEN  512
#define G3      1536      // 3*HIDDEN
#define NBLK    128       // scan blocks; 512 hidden units / 128 = 4 units/block
#define UPB     4         // units per block
#define CPB     12        // Wh columns per block (3 gates * UPB)
#define CHUNK   128       // timesteps per scan chunk-kernel
#define NCHUNK  4         // SEQ / CHUNK
#define HSLOT   (HIDDEN * BATCH)   // floats per h slot (128 KB)

typedef unsigned long long u64;
typedef unsigned int u32;

// ---------------------------------------------------------------------------
// Pack Wh slices: whp[blk][c][k] = Wh[k][ g*512 + blk*4 + u ]  (c = g*4+u)
// Contiguous in k -> wave-uniform weight reads scalarize (s_load). With no
// invalidation anywhere in the scan loop, each block's 24 KB slice stays
// L2-hot for the whole chunk.
// ---------------------------------------------------------------------------
__global__ __launch_bounds__(512) void prep_wh(const float* __restrict__ Wh,
                                               float* __restrict__ whp) {
    int t = blockIdx.x * 512 + threadIdx.x;      // 0 .. 786431
    int k   = t & 511;
    int cb  = t >> 9;          // blk*12 + c
    int c   = cb % 12;
    int blk = cb / 12;
    int u = c & 3, g = c >> 2;
    whp[t] = Wh[(long)k * G3 + g * HIDDEN + blk * UPB + u];
}

// ---------------------------------------------------------------------------
// Zero the 512 per-unit flags with agent-scope stores (the scan polls with
// L2-bypassing loads). Flags are monotonic global-step values across all
// 4 chunk kernels, so they are initialized exactly once per launch.
// ---------------------------------------------------------------------------
__global__ void init_flags(unsigned* flags) {
    __hip_atomic_store(&flags[threadIdx.x], 0u, __ATOMIC_RELAXED,
                       __HIP_MEMORY_SCOPE_AGENT);
}

// ---------------------------------------------------------------------------
// Chunked xg GEMM: xgC[col][lt][b] = emb[ids[b][s]] . Wx[:,col] + bx[col],
// s = chunk*CHUNK + lt. One 50 MB buffer reused per chunk; the consumer
// scan is a later kernel launch (entry-acquire) so reuse is coherent.
// ---------------------------------------------------------------------------
__global__ __launch_bounds__(256) void xg_gemm(const int* __restrict__ ids,
                                               const float* __restrict__ emb,
                                               const float* __restrict__ Wx,
                                               const float* __restrict__ bx,
                                               float* __restrict__ xgC,
                                               int chunk) {
    __shared__ float Es[64][68];   // Es[k][b], padded
    __shared__ float Ws[64][68];   // Ws[k][c], padded
    __shared__ int   sids[64];

    const int tid = threadIdx.x;
    const int nb = blockIdx.x;     // col tile 0..23
    const int lt = blockIdx.y;     // local timestep 0..127
    const int s  = chunk * CHUNK + lt;
    const int tn = tid & 15;
    const int tm = tid >> 4;

    if (tid < 64) sids[tid] = ids[tid * SEQ + s];   // id for batch=tid, step s
    __syncthreads();

    float acc[4][4];               // acc[i=col][j=b]
#pragma unroll
    for (int i = 0; i < 4; ++i)
#pragma unroll
        for (int j = 0; j < 4; ++j) acc[i][j] = 0.f;

    for (int kb = 0; kb < 256; kb += 64) {
#pragma unroll
        for (int p = 0; p < 4; ++p) {
            int b = p * 16 + tm;
            float4 av = *(const float4*)(emb + (long)sids[b] * DMODEL + kb + tn * 4);
            Es[tn * 4 + 0][b] = av.x;
            Es[tn * 4 + 1][b] = av.y;
            Es[tn * 4 + 2][b] = av.z;
            Es[tn * 4 + 3][b] = av.w;
            int krow = p * 16 + tm;
            float4 wv = *(const float4*)(Wx + (long)(kb + krow) * G3 + nb * 64 + tn * 4);
            *(float4*)&Ws[krow][tn * 4] = wv;
        }
        __syncthreads();
#pragma unroll
        for (int k = 0; k < 64; ++k) {
            float4 w4 = *(const float4*)&Ws[k][tm * 4];
            float4 e4 = *(const float4*)&Es[k][tn * 4];
            float ww[4] = {w4.x, w4.y, w4.z, w4.w};
            float ee[4] = {e4.x, e4.y, e4.z, e4.w};
#pragma unroll
            for (int i = 0; i < 4; ++i)
#pragma unroll
                for (int j = 0; j < 4; ++j)
                    acc[i][j] = fmaf(ww[i], ee[j], acc[i][j]);
        }
        __syncthreads();
    }

#pragma unroll
    for (int i = 0; i < 4; ++i) {
        int col = nb * 64 + tm * 4 + i;
        float bxi = bx[col];
        float4 o;
        o.x = acc[i][0] + bxi;
        o.y = acc[i][1] + bxi;
        o.z = acc[i][2] + bxi;
        o.w = acc[i][3] + bxi;
        *(float4*)(xgC + (long)col * (CHUNK * BATCH) + lt * 64 + tn * 4) = o;
    }
}

// ---------------------------------------------------------------------------
// GRU scan v11: cheap detection, expensive data -- exactly once.
// v10 (data-is-the-flag) exposed the congestion law: a failed data-poll
// iteration re-reads 16 KB/wave; with ~5-10 retries the GPU-wide poll
// traffic hits 80-240 MB/step of L2-bypassing reads -> MALL saturates ->
// visibility latency inflates -> more retries. The poll loop was the
// bottleneck it was waiting on.
// v11 splits detection from data movement so each pays its minimum:
//  * detection: per-unit flags (512). Consumer wave wu polls its 64
//    producer flags with ONE coalesced 256 B agent load per iteration --
//    64x less poll traffic than v10; MALL stays uncongested.
//  * data: ONE bulk agent read of 64 words into hv[64] after the flag
//    confirms, all loads in flight together (v10's register-resident
//    form, VGPR ~120), pinned ABOVE the FMA loop by sched_barrier(0) so
//    the compiler cannot re-fuse them into the FMA stream (v9 disease,
//    VGPR=52, serialized latency groups).
//  * agent scope for the bulk read on purpose: it bypasses L1/L2, so no
//    stale-line hazard from spatial prefetch of neighbor rows that were
//    not yet written when this wave's rows became valid. MALL is the
//    coherence point and always holds the write-through data.
//  * producer: store row (256 B write-through) -> per-wave vmcnt(0)
//    drain -> lane-0 flag store. No sentinel clears (4 dispatches and
//    ~33 MB of writes+evictions deleted).
// Correctness:
//  * flag >= t implies unit row of h[t] fully at MALL (store drained
//    before flag store; flags monotonic global-step values).
//  * skew bound: a block cannot pass step t's poll until every block
//    finished step t-1 => max skew 1 step << 128-slot reuse distance.
//  * chunk carry: slot 0 written by prev chunk's last step; lt==0 skips
//    the poll (kernel-boundary release/acquire covers visibility).
//    Chunk 0 skips step 0 analytically (h0 = 0).
// Deadlock-free: 128 blocks co-resident (<=256 CUs, one kernel at a
// time); all 8 waves reach the single per-step barrier; forward progress
// by induction on t.
// ---------------------------------------------------------------------------
__global__ __launch_bounds__(512, 2) void gru_scan(const float* __restrict__ whp,
                                                   const float* __restrict__ xgC,
                                                   const float* __restrict__ bh,
                                                   float* hist,
                                                   unsigned* flags,
                                                   int chunk) {
    const int tid = threadIdx.x;
    const int blk = blockIdx.x;
    const int b   = tid & 63;                                 // lane = batch
    const int wu  = __builtin_amdgcn_readfirstlane(tid >> 6); // wave 0..7

    __shared__ float part[2][8][CPB][64];   // 48 KB double-buffered partials

    const float* wb = whp + blk * (CPB * HIDDEN) + wu * 64;   // + c*512 + k
    const int base = chunk * CHUNK;

    // producer-wave state (waves 0-3 own unit jg = blk*4 + wu)
    int jg = 0;
    float bhr = 0.f, bhz = 0.f, bhn = 0.f, hprev = 0.f;
    const float* xr_p = nullptr; const float* xz_p = nullptr; const float* xn_p = nullptr;
    if (wu < 4) {
        jg  = blk * UPB + wu;
        bhr = bh[jg];
        bhz = bh[HIDDEN + jg];
        bhn = bh[2 * HIDDEN + jg];
        xr_p = xgC + (long)jg * (CHUNK * BATCH) + b;
        xz_p = xgC + (long)(HIDDEN + jg) * (CHUNK * BATCH) + b;
        xn_p = xgC + (long)(2 * HIDDEN + jg) * (CHUNK * BATCH) + b;
        // slot 0 holds h[base] (written by previous chunk kernel; fresh via
        // kernel-entry acquire). Chunk 0: h0 = 0.
        hprev = (chunk == 0) ? 0.f : hist[(long)jg * 64 + b];
    }

#pragma unroll 1
    for (int lt = 0; lt < CHUNK; ++lt) {
        const int t  = base + lt;
        const int pb = lt & 1;
        // this wave's 64 source units of h[t]: units wu*64 .. wu*64+63, batch b
        const u32* hq = (const u32*)(hist + (long)lt * HSLOT) + wu * (64 * 64) + b;
        float*     hw = hist + (long)((lt + 1) & (CHUNK - 1)) * HSLOT;   // h[t+1]

        // gate inputs: plain cached loads, issued before the poll so the
        // (possibly cold) fetch overlaps the wait.
        float xr = 0.f, xz = 0.f, xn = 0.f;
        if (wu < 4) {
            xr = xr_p[lt * 64];
            xz = xz_p[lt * 64];
            xn = xn_p[lt * 64];
        }

        float acc[CPB];
#pragma unroll
        for (int c = 0; c < CPB; ++c) acc[c] = 0.f;

        if (t > 0) {
            if (lt > 0) {
                // wave wu waits only for its 64 producer units' flags:
                // one coalesced 256 B agent load per iteration.
                const u32 tgt = (u32)t;
                for (;;) {
                    u32 f = __hip_atomic_load(&flags[wu * 64 + b], __ATOMIC_RELAXED,
                                              __HIP_MEMORY_SCOPE_AGENT);
                    if (__all((int)(f >= tgt))) break;
                    __builtin_amdgcn_s_sleep(1);
                }
            }
            // ONE bulk agent read: 64 parallel dword loads into registers.
            float hv[64];
#pragma unroll
            for (int i = 0; i < 64; ++i) {
                u32 w = __hip_atomic_load(hq + i * 64, __ATOMIC_RELAXED,
                                          __HIP_MEMORY_SCOPE_AGENT);
                hv[i] = __uint_as_float(w);
            }
            // pin: all loads issued above, no FMA hoisted between them
            __builtin_amdgcn_sched_barrier(0);
#pragma unroll
            for (int i = 0; i < 64; ++i) {
                const float hvv = hv[i];
#pragma unroll
                for (int c = 0; c < CPB; ++c)
                    acc[c] = fmaf(hvv, wb[c * HIDDEN + i], acc[c]);
            }
        }
        // else: h0 == 0 => partials are 0, hg = bh (analytic first step)

#pragma unroll
        for (int c = 0; c < CPB; ++c) part[pb][wu][c][b] = acc[c];
        __syncthreads();               // the ONLY barrier per step

        if (wu < 4) {
            __builtin_amdgcn_s_setprio(1);
            float hgr = bhr, hgz = bhz, hgn = bhn;
#pragma unroll
            for (int ww = 0; ww < 8; ++ww) {
                hgr += part[pb][ww][wu][b];
                hgz += part[pb][ww][4 + wu][b];
                hgn += part[pb][ww][8 + wu][b];
            }
            float r  = 1.f / (1.f + expf(-(xr + hgr)));
            float z  = 1.f / (1.f + expf(-(xz + hgz)));
            float nn = tanhf(xn + r * hgn);
            float hnew = (1.f - z) * nn + z * hprev;
            hprev = hnew;
            // publish: write-through row store, drain OWN store, then flag.
            __hip_atomic_store((u32*)hw + (long)jg * 64 + b, __float_as_uint(hnew),
                               __ATOMIC_RELAXED, __HIP_MEMORY_SCOPE_AGENT);
            asm volatile("s_waitcnt vmcnt(0)" ::: "memory");
            if (b == 0)
                __hip_atomic_store(&flags[jg], (u32)(t + 1), __ATOMIC_RELAXED,
                                   __HIP_MEMORY_SCOPE_AGENT);
            __builtin_amdgcn_s_setprio(0);
        }
        // waves 4-7 proceed straight to step t+1's poll; their part writes
        // target buffer (pb^1), which waves 0-3 are not reading.
    }
}

// ---------------------------------------------------------------------------
// head: logits[b][n] = sum_k h[k][b] * Wo[k][n] + bo[n]
// h[512] sits in hist slot 0 (written by chunk 3's last step), [u][b] layout.
// ---------------------------------------------------------------------------
__global__ void head_kernel(const float* __restrict__ hist,
                            const float* __restrict__ Wo,
                            const float* __restrict__ bo,
                            float* __restrict__ out) {
    int tid = threadIdx.x;        // 128 threads
    int b = tid >> 1, n = tid & 1;
    float acc = bo[n];
#pragma unroll 8
    for (int k = 0; k < HIDDEN; ++k)
        acc = fmaf(hist[(long)k * 64 + b], Wo[k * 2 + n], acc);
    out[b * 2 + n] = acc;
}

// ---------------------------------------------------------------------------
extern "C" void kernel_launch(void* const* d_in, const int* in_sizes, int n_in,
                              void* d_out, int out_size, void* d_ws, size_t ws_size,
                              hipStream_t stream) {
    (void)in_sizes; (void)n_in; (void)out_size; (void)ws_size;
    const int*   ids = (const int*)  d_in[0];
    const float* emb = (const float*)d_in[1];
    const float* Wx  = (const float*)d_in[2];
    const float* Wh  = (const float*)d_in[3];
    const float* bx  = (const float*)d_in[4];
    const float* bh  = (const float*)d_in[5];
    const float* Wo  = (const float*)d_in[6];
    const float* bo  = (const float*)d_in[7];
    float* out = (float*)d_out;

    char* ws = (char*)d_ws;
    // ws layout: [flags 2KB][hist 16MB][whp 3MB][xgC 50.3MB]  (~70 MB total)
    // hist needs NO init: every slot is written before it is read in every
    // kernel that reads it (chunk0/lt0 skips the read analytically).
    unsigned* flags = (unsigned*)ws;
    float* hist = (float*)(ws + 2048);
    float* whp  = (float*)(ws + 2048 + (size_t)CHUNK * HSLOT * 4);
    float* xgC  = (float*)(ws + 2048 + (size_t)CHUNK * HSLOT * 4
                           + (size_t)NBLK * CPB * HIDDEN * 4);

    init_flags<<<dim3(1), dim3(512), 0, stream>>>(flags);
    prep_wh<<<dim3(1536), dim3(512), 0, stream>>>(Wh, whp);
    for (int c = 0; c < NCHUNK; ++c) {
        xg_gemm<<<dim3(24, CHUNK), dim3(256), 0, stream>>>(ids, emb, Wx, bx, xgC, c);
        gru_scan<<<dim3(NBLK), dim3(512), 0, stream>>>(whp, xgC, bh, hist, flags, c);
    }
    head_kernel<<<dim3(1), dim3(128), 0, stream>>>(hist, Wo, bo, out);
}